// Round 1
// baseline (611.085 us; speedup 1.0000x reference)
//
#include <hip/hip_runtime.h>

#define N_ATOMS 20000
#define HIDDEN  128
#define BATCH   16
#define N_BONDS 60000

// Workspace layout (floats):
//   [0, 20000)            deg
//   [20000, 20012)        Mc   (M row-major 9 floats, then c 3 floats)
//   [20016, 20016+960000) agg  (B * N * 3)
#define WS_DEG_OFF 0
#define WS_MC_OFF  20000
#define WS_AGG_OFF 20016
#define WS_TOTAL_FLOATS (WS_AGG_OFF + BATCH * N_ATOMS * 3)

__global__ void zero_kernel(float* __restrict__ p, int n) {
    int i = blockIdx.x * blockDim.x + threadIdx.x;
    int stride = gridDim.x * blockDim.x;
    for (; i < n; i += stride) p[i] = 0.0f;
}

__global__ void deg_kernel(const int* __restrict__ bonds, float* __restrict__ deg) {
    int e = blockIdx.x * blockDim.x + threadIdx.x;
    if (e >= N_BONDS) return;
    int a = bonds[2 * e];
    int b = bonds[2 * e + 1];
    atomicAdd(&deg[a], 1.0f);
    atomicAdd(&deg[b], 1.0f);
}

// M[i][j] = sum_k W_msg[i*128+k] * W_upd[k*3+j]   (i,j in 0..2)
// c[j]    = sum_k b_msg[k]       * W_upd[k*3+j]
__global__ void mc_kernel(const float* __restrict__ W_msg, const float* __restrict__ b_msg,
                          const float* __restrict__ W_upd, float* __restrict__ Mc) {
    int t = threadIdx.x;
    if (t >= 12) return;
    float s = 0.0f;
    if (t < 9) {
        int i = t / 3, j = t % 3;
        for (int k = 0; k < HIDDEN; ++k) s += W_msg[i * HIDDEN + k] * W_upd[k * 3 + j];
    } else {
        int j = t - 9;
        for (int k = 0; k < HIDDEN; ++k) s += b_msg[k] * W_upd[k * 3 + j];
    }
    Mc[t] = s;
}

// agg[b, dst] += h[b, src] for both edge directions.
__global__ void scatter_kernel(const float* __restrict__ h, const int* __restrict__ bonds,
                               float* __restrict__ agg) {
    int e = blockIdx.x * blockDim.x + threadIdx.x;
    if (e >= N_BONDS) return;
    int b = blockIdx.y;
    int a0 = bonds[2 * e];
    int a1 = bonds[2 * e + 1];
    const float* hb = h + (size_t)b * N_ATOMS * 3;
    float* ab = agg + (size_t)b * N_ATOMS * 3;
    float x0 = hb[a0 * 3 + 0], y0 = hb[a0 * 3 + 1], z0 = hb[a0 * 3 + 2];
    float x1 = hb[a1 * 3 + 0], y1 = hb[a1 * 3 + 1], z1 = hb[a1 * 3 + 2];
    atomicAdd(&ab[a1 * 3 + 0], x0);
    atomicAdd(&ab[a1 * 3 + 1], y0);
    atomicAdd(&ab[a1 * 3 + 2], z0);
    atomicAdd(&ab[a0 * 3 + 0], x1);
    atomicAdd(&ab[a0 * 3 + 1], y1);
    atomicAdd(&ab[a0 * 3 + 2], z1);
}

// out[b,n] = h_in[b,n] + inv_deg[n] * (agg[b,n] @ M) + (deg>0 ? c : 0) + b_upd
__global__ void update_kernel(const float* __restrict__ h_in, const float* __restrict__ agg,
                              const float* __restrict__ deg, const float* __restrict__ Mc,
                              const float* __restrict__ b_upd, float* __restrict__ out) {
    int n = blockIdx.x * blockDim.x + threadIdx.x;
    if (n >= N_ATOMS) return;
    int b = blockIdx.y;
    size_t base = (size_t)b * N_ATOMS * 3 + (size_t)n * 3;
    float d = deg[n];
    float inv = d > 0.0f ? 1.0f / d : 0.0f;
    float flag = d > 0.0f ? 1.0f : 0.0f;
    float a0 = agg[base + 0], a1 = agg[base + 1], a2 = agg[base + 2];
    float m00 = Mc[0], m01 = Mc[1], m02 = Mc[2];
    float m10 = Mc[3], m11 = Mc[4], m12 = Mc[5];
    float m20 = Mc[6], m21 = Mc[7], m22 = Mc[8];
    float c0 = Mc[9], c1 = Mc[10], c2 = Mc[11];
    float t0 = inv * (a0 * m00 + a1 * m10 + a2 * m20) + flag * c0 + b_upd[0];
    float t1 = inv * (a0 * m01 + a1 * m11 + a2 * m21) + flag * c1 + b_upd[1];
    float t2 = inv * (a0 * m02 + a1 * m12 + a2 * m22) + flag * c2 + b_upd[2];
    out[base + 0] = h_in[base + 0] + t0;
    out[base + 1] = h_in[base + 1] + t1;
    out[base + 2] = h_in[base + 2] + t2;
}

extern "C" void kernel_launch(void* const* d_in, const int* in_sizes, int n_in,
                              void* d_out, int out_size, void* d_ws, size_t ws_size,
                              hipStream_t stream) {
    const float* positions = (const float*)d_in[0];
    const int* bonds = (const int*)d_in[1];
    const float* W_msg = (const float*)d_in[2];
    const float* b_msg = (const float*)d_in[3];
    const float* W_upd = (const float*)d_in[4];
    const float* b_upd = (const float*)d_in[5];
    float* out = (float*)d_out;

    float* ws = (float*)d_ws;
    float* deg = ws + WS_DEG_OFF;
    float* Mc = ws + WS_MC_OFF;
    float* agg = ws + WS_AGG_OFF;

    const int AGG_FLOATS = BATCH * N_ATOMS * 3;

    // Zero deg + Mc + agg.
    {
        int n = WS_TOTAL_FLOATS;
        int blocks = 1024;
        zero_kernel<<<blocks, 256, 0, stream>>>(ws, n);
    }
    // Degree.
    deg_kernel<<<(N_BONDS + 255) / 256, 256, 0, stream>>>(bonds, deg);
    // M and c.
    mc_kernel<<<1, 64, 0, stream>>>(W_msg, b_msg, W_upd, Mc);

    dim3 sgrid((N_BONDS + 255) / 256, BATCH, 1);
    dim3 ugrid((N_ATOMS + 255) / 256, BATCH, 1);

    // Iteration 1: h = positions -> out
    scatter_kernel<<<sgrid, 256, 0, stream>>>(positions, bonds, agg);
    update_kernel<<<ugrid, 256, 0, stream>>>(positions, agg, deg, Mc, b_upd, out);

    // Zero agg for iteration 2.
    zero_kernel<<<1024, 256, 0, stream>>>(agg, AGG_FLOATS);

    // Iteration 2: h = out -> out (in-place per-node update)
    scatter_kernel<<<sgrid, 256, 0, stream>>>(out, bonds, agg);
    update_kernel<<<ugrid, 256, 0, stream>>>(out, agg, deg, Mc, b_upd, out);
}

// Round 2
// 107.817 us; speedup vs baseline: 5.6678x; 5.6678x over previous
//
#include <hip/hip_runtime.h>

#define N_ATOMS 20000
#define BATCH   16
#define N_BONDS 60000
#define NDIR    (2 * N_BONDS)

// Workspace layout:
//   int  deg[N_ATOMS]
//   int  offsets[N_ATOMS + 1]
//   int  cursor[N_ATOMS]
//   int  adj[NDIR]
//   float Mc[12]                 (M row-major 9, then c 3)
//   float h1[BATCH * N_ATOMS * 3]
#define OFF_DEG     0
#define OFF_OFFSETS (OFF_DEG + N_ATOMS)
#define OFF_CURSOR  (OFF_OFFSETS + N_ATOMS + 1)
#define OFF_ADJ     (OFF_CURSOR + N_ATOMS)
#define OFF_MC      (OFF_ADJ + NDIR)
#define OFF_H1      (OFF_MC + 16)   // keep 16-byte-ish alignment

__global__ void zero_deg_kernel(int* __restrict__ deg) {
    int i = blockIdx.x * blockDim.x + threadIdx.x;
    if (i < N_ATOMS) deg[i] = 0;
}

__global__ void deg_kernel(const int* __restrict__ bonds, int* __restrict__ deg) {
    int e = blockIdx.x * blockDim.x + threadIdx.x;
    if (e >= N_BONDS) return;
    int a = bonds[2 * e];
    int b = bonds[2 * e + 1];
    atomicAdd(&deg[a], 1);
    atomicAdd(&deg[b], 1);
}

// Single-block exclusive scan over deg -> offsets (and cursor copy).
__global__ __launch_bounds__(1024) void scan_kernel(const int* __restrict__ deg,
                                                    int* __restrict__ offsets,
                                                    int* __restrict__ cursor) {
    __shared__ int tmp[1024];
    __shared__ int carry;
    if (threadIdx.x == 0) carry = 0;
    __syncthreads();
    for (int base = 0; base < N_ATOMS; base += 1024) {
        int i = base + (int)threadIdx.x;
        int v = (i < N_ATOMS) ? deg[i] : 0;
        tmp[threadIdx.x] = v;
        __syncthreads();
        for (int off = 1; off < 1024; off <<= 1) {
            int t = (threadIdx.x >= (unsigned)off) ? tmp[threadIdx.x - off] : 0;
            __syncthreads();
            tmp[threadIdx.x] += t;
            __syncthreads();
        }
        int excl = carry + tmp[threadIdx.x] - v;
        if (i < N_ATOMS) { offsets[i] = excl; cursor[i] = excl; }
        __syncthreads();
        if (threadIdx.x == 1023) carry += tmp[1023];
        __syncthreads();
    }
    if (threadIdx.x == 0) offsets[N_ATOMS] = carry;
}

// Fill adjacency: for each directed edge (src -> dst), adj[slot(dst)] = src.
__global__ void fill_adj_kernel(const int* __restrict__ bonds, int* __restrict__ cursor,
                                int* __restrict__ adj) {
    int e = blockIdx.x * blockDim.x + threadIdx.x;
    if (e >= N_BONDS) return;
    int a0 = bonds[2 * e];
    int a1 = bonds[2 * e + 1];
    int p1 = atomicAdd(&cursor[a1], 1);
    adj[p1] = a0;
    int p0 = atomicAdd(&cursor[a0], 1);
    adj[p0] = a1;
}

// M[i][j] = sum_k W_msg[i*128+k] * W_upd[k*3+j]; c[j] = sum_k b_msg[k]*W_upd[k*3+j]
__global__ void mc_kernel(const float* __restrict__ W_msg, const float* __restrict__ b_msg,
                          const float* __restrict__ W_upd, float* __restrict__ Mc) {
    int t = threadIdx.x;
    if (t >= 12) return;
    float s = 0.0f;
    if (t < 9) {
        int i = t / 3, j = t % 3;
        for (int k = 0; k < 128; ++k) s += W_msg[i * 128 + k] * W_upd[k * 3 + j];
    } else {
        int j = t - 9;
        for (int k = 0; k < 128; ++k) s += b_msg[k] * W_upd[k * 3 + j];
    }
    Mc[t] = s;
}

// out[b,n] = h[b,n] + inv_deg * (sum_{j in adj(n)} h[b,j]) @ M + flag*c + b_upd
__global__ void fused_iter_kernel(const float* __restrict__ h, const int* __restrict__ offsets,
                                  const int* __restrict__ adj, const float* __restrict__ Mc,
                                  const float* __restrict__ b_upd, float* __restrict__ out) {
    int n = blockIdx.x * blockDim.x + threadIdx.x;
    if (n >= N_ATOMS) return;
    int b = blockIdx.y;
    const float* hb = h + (size_t)b * N_ATOMS * 3;
    int beg = offsets[n], end = offsets[n + 1];
    float sx = 0.0f, sy = 0.0f, sz = 0.0f;
    for (int k = beg; k < end; ++k) {
        int j = adj[k];
        sx += hb[j * 3 + 0];
        sy += hb[j * 3 + 1];
        sz += hb[j * 3 + 2];
    }
    int d = end - beg;
    float inv = d > 0 ? 1.0f / (float)d : 0.0f;
    float flag = d > 0 ? 1.0f : 0.0f;
    float m00 = Mc[0], m01 = Mc[1], m02 = Mc[2];
    float m10 = Mc[3], m11 = Mc[4], m12 = Mc[5];
    float m20 = Mc[6], m21 = Mc[7], m22 = Mc[8];
    float c0 = Mc[9], c1 = Mc[10], c2 = Mc[11];
    size_t base = (size_t)b * N_ATOMS * 3 + (size_t)n * 3;
    float t0 = inv * (sx * m00 + sy * m10 + sz * m20) + flag * c0 + b_upd[0];
    float t1 = inv * (sx * m01 + sy * m11 + sz * m21) + flag * c1 + b_upd[1];
    float t2 = inv * (sx * m02 + sy * m12 + sz * m22) + flag * c2 + b_upd[2];
    out[base + 0] = h[base + 0] + t0;
    out[base + 1] = h[base + 1] + t1;
    out[base + 2] = h[base + 2] + t2;
}

extern "C" void kernel_launch(void* const* d_in, const int* in_sizes, int n_in,
                              void* d_out, int out_size, void* d_ws, size_t ws_size,
                              hipStream_t stream) {
    const float* positions = (const float*)d_in[0];
    const int* bonds = (const int*)d_in[1];
    const float* W_msg = (const float*)d_in[2];
    const float* b_msg = (const float*)d_in[3];
    const float* W_upd = (const float*)d_in[4];
    const float* b_upd = (const float*)d_in[5];
    float* out = (float*)d_out;

    int* wsi = (int*)d_ws;
    int* deg = wsi + OFF_DEG;
    int* offsets = wsi + OFF_OFFSETS;
    int* cursor = wsi + OFF_CURSOR;
    int* adj = wsi + OFF_ADJ;
    float* Mc = (float*)(wsi + OFF_MC);
    float* h1 = (float*)(wsi + OFF_H1);

    // CSR build
    zero_deg_kernel<<<(N_ATOMS + 255) / 256, 256, 0, stream>>>(deg);
    deg_kernel<<<(N_BONDS + 255) / 256, 256, 0, stream>>>(bonds, deg);
    scan_kernel<<<1, 1024, 0, stream>>>(deg, offsets, cursor);
    fill_adj_kernel<<<(N_BONDS + 255) / 256, 256, 0, stream>>>(bonds, cursor, adj);
    mc_kernel<<<1, 64, 0, stream>>>(W_msg, b_msg, W_upd, Mc);

    dim3 fgrid((N_ATOMS + 255) / 256, BATCH, 1);
    // Iteration 1: positions -> h1
    fused_iter_kernel<<<fgrid, 256, 0, stream>>>(positions, offsets, adj, Mc, b_upd, h1);
    // Iteration 2: h1 -> out
    fused_iter_kernel<<<fgrid, 256, 0, stream>>>(h1, offsets, adj, Mc, b_upd, out);
}

// Round 3
// 96.737 us; speedup vs baseline: 6.3170x; 1.1145x over previous
//
#include <hip/hip_runtime.h>

#define N_ATOMS 20000
#define BATCH   16
#define N_BONDS 60000
#define NDIR    (2 * N_BONDS)

// Workspace layout (int-indexed):
//   int  deg[N_ATOMS]
//   int  offsets[N_ATOMS + 1]
//   int  cursor[N_ATOMS]
//   int  adj[NDIR]
//   float Mc[12]                     (M row-major 9, then c 3)
//   float h1[BATCH * N_ATOMS * 4]    (padded xyz_, for float4 gather)
#define OFF_DEG     0
#define OFF_OFFSETS (OFF_DEG + N_ATOMS)
#define OFF_CURSOR  (OFF_OFFSETS + N_ATOMS + 1)
#define OFF_ADJ     (OFF_CURSOR + N_ATOMS)
#define OFF_MC      180004
#define OFF_H1      180016   // multiple of 4 -> 16B aligned

__global__ void zero_deg_kernel(int* __restrict__ deg) {
    int i = blockIdx.x * blockDim.x + threadIdx.x;
    if (i < N_ATOMS) deg[i] = 0;
}

__global__ void deg_kernel(const int* __restrict__ bonds, int* __restrict__ deg) {
    int e = blockIdx.x * blockDim.x + threadIdx.x;
    if (e >= N_BONDS) return;
    int a = bonds[2 * e];
    int b = bonds[2 * e + 1];
    atomicAdd(&deg[a], 1);
    atomicAdd(&deg[b], 1);
}

// Single-block scan, register-chunked: each thread owns CH=20 contiguous
// elements (serial exclusive scan in regs), then one 1024-wide Hillis-Steele
// over thread totals (20 barriers total, vs ~400 in the naive version).
#define SCAN_T  1024
#define SCAN_CH 20
__global__ __launch_bounds__(SCAN_T) void scan_kernel(const int* __restrict__ deg,
                                                      int* __restrict__ offsets,
                                                      int* __restrict__ cursor) {
    __shared__ int sums[SCAN_T];
    int t = threadIdx.x;
    int beg = t * SCAN_CH;
    int loc[SCAN_CH];
    int run = 0;
#pragma unroll
    for (int k = 0; k < SCAN_CH; ++k) {
        int i = beg + k;
        loc[k] = run;
        if (i < N_ATOMS) run += deg[i];
    }
    sums[t] = run;
    __syncthreads();
    int acc = run;
    for (int off = 1; off < SCAN_T; off <<= 1) {
        int v = (t >= off) ? sums[t - off] : 0;
        __syncthreads();
        acc += v;
        sums[t] = acc;
        __syncthreads();
    }
    int prefix = acc - run;  // exclusive prefix of this thread's chunk
#pragma unroll
    for (int k = 0; k < SCAN_CH; ++k) {
        int i = beg + k;
        if (i < N_ATOMS) {
            int o = prefix + loc[k];
            offsets[i] = o;
            cursor[i] = o;
        }
    }
    if (t == SCAN_T - 1) offsets[N_ATOMS] = acc;
}

__global__ void fill_adj_kernel(const int* __restrict__ bonds, int* __restrict__ cursor,
                                int* __restrict__ adj) {
    int e = blockIdx.x * blockDim.x + threadIdx.x;
    if (e >= N_BONDS) return;
    int a0 = bonds[2 * e];
    int a1 = bonds[2 * e + 1];
    int p1 = atomicAdd(&cursor[a1], 1);
    adj[p1] = a0;
    int p0 = atomicAdd(&cursor[a0], 1);
    adj[p0] = a1;
}

// M[i][j] = sum_k W_msg[i*128+k] * W_upd[k*3+j]; c[j] = sum_k b_msg[k]*W_upd[k*3+j]
__global__ void mc_kernel(const float* __restrict__ W_msg, const float* __restrict__ b_msg,
                          const float* __restrict__ W_upd, float* __restrict__ Mc) {
    int t = threadIdx.x;
    if (t >= 12) return;
    float s = 0.0f;
    if (t < 9) {
        int i = t / 3, j = t % 3;
        for (int k = 0; k < 128; ++k) s += W_msg[i * 128 + k] * W_upd[k * 3 + j];
    } else {
        int j = t - 9;
        for (int k = 0; k < 128; ++k) s += b_msg[k] * W_upd[k * 3 + j];
    }
    Mc[t] = s;
}

// out[b,n] = h[b,n] + inv_deg * (sum_{j in adj(n)} h[b,j]) @ M + flag*c + b_upd
// INS/OUTS: per-node float stride of input/output (3 = packed, 4 = padded float4).
template <int INS, int OUTS>
__global__ void fused_iter_kernel(const float* __restrict__ h, const int* __restrict__ offsets,
                                  const int* __restrict__ adj, const float* __restrict__ Mc,
                                  const float* __restrict__ b_upd, float* __restrict__ out) {
    int n = blockIdx.x * blockDim.x + threadIdx.x;
    if (n >= N_ATOMS) return;
    int b = blockIdx.y;
    const float* hb = h + (size_t)b * N_ATOMS * INS;
    int beg = offsets[n], end = offsets[n + 1];
    float sx = 0.0f, sy = 0.0f, sz = 0.0f;
    if (INS == 4) {
        for (int k = beg; k < end; ++k) {
            int j = adj[k];
            float4 v = *(const float4*)(hb + (size_t)j * 4);
            sx += v.x; sy += v.y; sz += v.z;
        }
    } else {
        for (int k = beg; k < end; ++k) {
            int j = adj[k];
            sx += hb[j * 3 + 0];
            sy += hb[j * 3 + 1];
            sz += hb[j * 3 + 2];
        }
    }
    int d = end - beg;
    float inv = d > 0 ? 1.0f / (float)d : 0.0f;
    float flag = d > 0 ? 1.0f : 0.0f;
    float m00 = Mc[0], m01 = Mc[1], m02 = Mc[2];
    float m10 = Mc[3], m11 = Mc[4], m12 = Mc[5];
    float m20 = Mc[6], m21 = Mc[7], m22 = Mc[8];
    float c0 = Mc[9], c1 = Mc[10], c2 = Mc[11];
    float t0 = inv * (sx * m00 + sy * m10 + sz * m20) + flag * c0 + b_upd[0];
    float t1 = inv * (sx * m01 + sy * m11 + sz * m21) + flag * c1 + b_upd[1];
    float t2 = inv * (sx * m02 + sy * m12 + sz * m22) + flag * c2 + b_upd[2];
    size_t ibase = (size_t)b * N_ATOMS * INS + (size_t)n * INS;
    size_t obase = (size_t)b * N_ATOMS * OUTS + (size_t)n * OUTS;
    float hx, hy, hz;
    if (INS == 4) {
        float4 v = *(const float4*)(h + ibase);
        hx = v.x; hy = v.y; hz = v.z;
    } else {
        hx = h[ibase + 0]; hy = h[ibase + 1]; hz = h[ibase + 2];
    }
    float o0 = hx + t0, o1 = hy + t1, o2 = hz + t2;
    if (OUTS == 4) {
        *(float4*)(out + obase) = make_float4(o0, o1, o2, 0.0f);
    } else {
        out[obase + 0] = o0;
        out[obase + 1] = o1;
        out[obase + 2] = o2;
    }
}

extern "C" void kernel_launch(void* const* d_in, const int* in_sizes, int n_in,
                              void* d_out, int out_size, void* d_ws, size_t ws_size,
                              hipStream_t stream) {
    const float* positions = (const float*)d_in[0];
    const int* bonds = (const int*)d_in[1];
    const float* W_msg = (const float*)d_in[2];
    const float* b_msg = (const float*)d_in[3];
    const float* W_upd = (const float*)d_in[4];
    const float* b_upd = (const float*)d_in[5];
    float* out = (float*)d_out;

    int* wsi = (int*)d_ws;
    int* deg = wsi + OFF_DEG;
    int* offsets = wsi + OFF_OFFSETS;
    int* cursor = wsi + OFF_CURSOR;
    int* adj = wsi + OFF_ADJ;
    float* Mc = (float*)(wsi + OFF_MC);
    float* h1 = (float*)(wsi + OFF_H1);

    // CSR build
    zero_deg_kernel<<<(N_ATOMS + 255) / 256, 256, 0, stream>>>(deg);
    deg_kernel<<<(N_BONDS + 255) / 256, 256, 0, stream>>>(bonds, deg);
    scan_kernel<<<1, SCAN_T, 0, stream>>>(deg, offsets, cursor);
    fill_adj_kernel<<<(N_BONDS + 255) / 256, 256, 0, stream>>>(bonds, cursor, adj);
    mc_kernel<<<1, 64, 0, stream>>>(W_msg, b_msg, W_upd, Mc);  // off critical path

    dim3 fgrid((N_ATOMS + 255) / 256, BATCH, 1);
    // Iteration 1: positions (packed) -> h1 (padded)
    fused_iter_kernel<3, 4><<<fgrid, 256, 0, stream>>>(positions, offsets, adj, Mc, b_upd, h1);
    // Iteration 2: h1 (padded) -> out (packed)
    fused_iter_kernel<4, 3><<<fgrid, 256, 0, stream>>>(h1, offsets, adj, Mc, b_upd, out);
}